// Round 13
// baseline (2138.420 us; speedup 1.0000x reference)
//
#include <hip/hip_runtime.h>
#include <hip/hip_cooperative_groups.h>
#include <math.h>

namespace cg = cooperative_groups;

#define NNODE 2048
#define NEDGE 65536
#define HIDN  256
#define NHEAD 8
#define HDIM  32
#define FFD   1024
#define NLAYER 4
#define OUTD  1280
#define NNZ_MAX (2*NEDGE + NNODE)

typedef __attribute__((ext_vector_type(8))) short bf16x8;
typedef __attribute__((ext_vector_type(4))) float f32x4;

__device__ __forceinline__ unsigned short f2b(float f) {
    unsigned u = __float_as_uint(f);
    unsigned r = (u + 0x7fffu + ((u >> 16) & 1u)) >> 16;
    return (unsigned short)r;
}
__device__ __forceinline__ float b2f(unsigned short u) {
    return __uint_as_float((unsigned)u << 16);
}

// ------------------------------------------- standalone MFMA GEMM (R9) -----
template<int K, int EPI, int OUT>
__global__ __launch_bounds__(256)
void mgemm(const unsigned short* __restrict__ A, const unsigned short* __restrict__ Bt,
           const float* __restrict__ bias, const float* __restrict__ extra,
           float* __restrict__ Cf, unsigned short* __restrict__ Cb,
           int M, int N, const float* __restrict__ Wp2, float* __restrict__ sred)
{
    __shared__ __align__(16) unsigned short As[2][32 * 40];
    __shared__ __align__(16) unsigned short Bs[2][64 * 40];
    int tid = threadIdx.x;
    int bm0 = blockIdx.y * 32, bn0 = blockIdx.x * 64;
    int wave = tid >> 6, lane = tid & 63;
    int wm = (wave >> 1) * 16;
    int wn = (wave & 1) * 32;
    int lrow = lane & 15, quad = lane >> 4;
    int brow = tid >> 2, koff = (tid & 3) * 8;
    int arow = (tid & 127) >> 2;
    bool doA = tid < 128;
    const unsigned short* ap = A  + (size_t)(bm0 + arow) * K + koff;
    const unsigned short* bp = Bt + (size_t)(bn0 + brow) * K + koff;
    uint4 av, bv;
    if (doA) av = *(const uint4*)ap;
    bv = *(const uint4*)bp;
    constexpr int NC = K / 32;
    if (doA) *(uint4*)(&As[0][arow*40 + koff]) = av;
    *(uint4*)(&Bs[0][brow*40 + koff]) = bv;
    __syncthreads();
    f32x4 acc[2] = {};
    #pragma unroll 8
    for (int c = 0; c < NC; ++c) {
        int cur = c & 1;
        if (c + 1 < NC) {
            if (doA) av = *(const uint4*)(ap + (c+1)*32);
            bv = *(const uint4*)(bp + (c+1)*32);
        }
        bf16x8 af = *(const bf16x8*)(&As[cur][(wm + lrow)*40 + quad*8]);
        bf16x8 b0 = *(const bf16x8*)(&Bs[cur][(wn + lrow)*40 + quad*8]);
        bf16x8 b1 = *(const bf16x8*)(&Bs[cur][(wn + 16 + lrow)*40 + quad*8]);
        acc[0] = __builtin_amdgcn_mfma_f32_16x16x32_bf16(af, b0, acc[0], 0, 0, 0);
        acc[1] = __builtin_amdgcn_mfma_f32_16x16x32_bf16(af, b1, acc[1], 0, 0, 0);
        if (c + 1 < NC) {
            if (doA) *(uint4*)(&As[cur^1][arow*40 + koff]) = av;
            *(uint4*)(&Bs[cur^1][brow*40 + koff]) = bv;
        }
        __syncthreads();
    }
    if (EPI == 4) {
        #pragma unroll
        for (int r = 0; r < 4; r++) {
            int row = bm0 + wm + quad*4 + r;
            float ps = 0.f;
            #pragma unroll
            for (int j = 0; j < 2; j++) {
                int col = bn0 + wn + j*16 + lrow;
                float v = tanhf(acc[j][r] + bias[col]);
                ps += v * Wp2[col];
            }
            ps += __shfl_xor(ps, 1);
            ps += __shfl_xor(ps, 2);
            ps += __shfl_xor(ps, 4);
            ps += __shfl_xor(ps, 8);
            if (lrow == 0) atomicAdd(&sred[row], ps);
        }
        return;
    }
    #pragma unroll
    for (int j = 0; j < 2; j++) {
        int col = bn0 + wn + j*16 + lrow;
        float bvv = bias[col];
        #pragma unroll
        for (int r = 0; r < 4; r++) {
            int row = bm0 + wm + quad*4 + r;
            float v = acc[j][r] + bvv;
            if (EPI == 1) v = 0.5f * v * (1.f + erff(v * 0.70710678118654752f));
            else if (EPI == 3) v += extra[(size_t)row*N + col];
            if (OUT == 0 || OUT == 2) Cf[(size_t)row*N + col] = v;
            if (OUT == 1 || OUT == 2) Cb[(size_t)row*N + col] = f2b(v);
        }
    }
}

// ============================ megakernel device pieces =====================
struct MegaArgs {
    float* x;
    unsigned short* xb;
    unsigned short* bufQKVb;
    unsigned short* bufAb;
    float* bufO;
    unsigned short* bufFb;
    const unsigned short* WqkvT;
    const unsigned short* WoT;
    const unsigned short* Wf1T;
    const unsigned short* Wf2T;
    const float* bqkv;
    const float* bo;
    const float* bf1;
    const float* bf2;
    const float* g1; const float* be1;
    const float* g2; const float* be2;
    const float* g_ln; const float* b_ln;
    const int* rowoff;
    const int* cols;
    const float* bias_csr;
};

template<int K, int EPI, int OUT>
__device__ __forceinline__ void d_mgemm(int bn_t, int bm_t,
    const unsigned short* A, const unsigned short* Bt,
    const float* bias, float* Cf, unsigned short* Cb, int N,
    unsigned short (&As)[2][32*40], unsigned short (&Bs)[2][64*40])
{
    int tid = threadIdx.x;
    int bm0 = bm_t * 32, bn0 = bn_t * 64;
    int wave = tid >> 6, lane = tid & 63;
    int wm = (wave >> 1) * 16;
    int wn = (wave & 1) * 32;
    int lrow = lane & 15, quad = lane >> 4;
    int brow = tid >> 2, koff = (tid & 3) * 8;
    int arow = (tid & 127) >> 2;
    bool doA = tid < 128;
    const unsigned short* ap = A  + (size_t)(bm0 + arow) * K + koff;
    const unsigned short* bp = Bt + (size_t)(bn0 + brow) * K + koff;
    uint4 av, bv;
    if (doA) av = *(const uint4*)ap;
    bv = *(const uint4*)bp;
    constexpr int NC = K / 32;
    if (doA) *(uint4*)(&As[0][arow*40 + koff]) = av;
    *(uint4*)(&Bs[0][brow*40 + koff]) = bv;
    __syncthreads();
    f32x4 acc[2] = {};
    #pragma unroll 8
    for (int c = 0; c < NC; ++c) {
        int cur = c & 1;
        if (c + 1 < NC) {
            if (doA) av = *(const uint4*)(ap + (c+1)*32);
            bv = *(const uint4*)(bp + (c+1)*32);
        }
        bf16x8 af = *(const bf16x8*)(&As[cur][(wm + lrow)*40 + quad*8]);
        bf16x8 b0 = *(const bf16x8*)(&Bs[cur][(wn + lrow)*40 + quad*8]);
        bf16x8 b1 = *(const bf16x8*)(&Bs[cur][(wn + 16 + lrow)*40 + quad*8]);
        acc[0] = __builtin_amdgcn_mfma_f32_16x16x32_bf16(af, b0, acc[0], 0, 0, 0);
        acc[1] = __builtin_amdgcn_mfma_f32_16x16x32_bf16(af, b1, acc[1], 0, 0, 0);
        if (c + 1 < NC) {
            if (doA) *(uint4*)(&As[cur^1][arow*40 + koff]) = av;
            *(uint4*)(&Bs[cur^1][brow*40 + koff]) = bv;
        }
        __syncthreads();
    }
    #pragma unroll
    for (int j = 0; j < 2; j++) {
        int col = bn0 + wn + j*16 + lrow;
        float bvv = bias[col];
        #pragma unroll
        for (int r = 0; r < 4; r++) {
            int row = bm0 + wm + quad*4 + r;
            float v = acc[j][r] + bvv;
            if (EPI == 1) v = 0.5f * v * (1.f + erff(v * 0.70710678118654752f));
            if (OUT == 0) Cf[(size_t)row*N + col] = v;
            else          Cb[(size_t)row*N + col] = f2b(v);
        }
    }
}

__device__ __forceinline__ void d_attn(int i, const unsigned short* QKVb,
    const int* rowoff, const int* cols, const float* bias_csr,
    unsigned short* ctxb, int layer,
    float (&mS)[4][8], float (&lS)[4][8], float (&accS)[4][256])
{
    __syncthreads();
    int tid = threadIdx.x;
    int w = tid >> 6, lane = tid & 63;
    int h = lane >> 3;
    int off = lane * 4;
    ushort4 qu = *(const ushort4*)(QKVb + (size_t)i*768 + off);
    float4 qf = { b2f(qu.x), b2f(qu.y), b2f(qu.z), b2f(qu.w) };
    int start = rowoff[i], end = rowoff[i+1];
    int lh0 = layer * 8 + h;
    float m = -INFINITY, l = 0.f;
    float4 acc = {0.f, 0.f, 0.f, 0.f};
    for (int c0 = start + w; c0 < end; c0 += 256) {
        int myslot = c0 + 4*lane;
        int mycol = (myslot < end) ? cols[myslot] : 0;
        int lim = min(end, c0 + 256);
        int it = 0;
        for (int slot = c0; slot < lim; slot += 4, ++it) {
            int j = __shfl(mycol, it);
            ushort4 ku = *(const ushort4*)(QKVb + (size_t)j*768 + 256 + off);
            float s = qf.x*b2f(ku.x) + qf.y*b2f(ku.y) + qf.z*b2f(ku.z) + qf.w*b2f(ku.w);
            s += __shfl_xor(s, 1);
            s += __shfl_xor(s, 2);
            s += __shfl_xor(s, 4);
            s = s * 0.17677669529663687f + bias_csr[(size_t)slot*32 + lh0];
            float mn = fmaxf(m, s);
            float sc = __expf(m - mn);
            float p  = __expf(s - mn);
            ushort4 vu = *(const ushort4*)(QKVb + (size_t)j*768 + 512 + off);
            acc.x = acc.x*sc + p*b2f(vu.x);
            acc.y = acc.y*sc + p*b2f(vu.y);
            acc.z = acc.z*sc + p*b2f(vu.z);
            acc.w = acc.w*sc + p*b2f(vu.w);
            l = l*sc + p;
            m = mn;
        }
    }
    if ((lane & 7) == 0) { mS[w][h] = m; lS[w][h] = l; }
    *(float4*)&accS[w][off] = acc;
    __syncthreads();
    if (w == 0) {
        float m0 = mS[0][h], m1 = mS[1][h], m2 = mS[2][h], m3 = mS[3][h];
        float mx = fmaxf(fmaxf(m0, m1), fmaxf(m2, m3));
        float e0 = (m0 == -INFINITY) ? 0.f : __expf(m0 - mx);
        float e1 = (m1 == -INFINITY) ? 0.f : __expf(m1 - mx);
        float e2 = (m2 == -INFINITY) ? 0.f : __expf(m2 - mx);
        float e3 = (m3 == -INFINITY) ? 0.f : __expf(m3 - mx);
        float ls = lS[0][h]*e0 + lS[1][h]*e1 + lS[2][h]*e2 + lS[3][h]*e3;
        float4 a0 = *(float4*)&accS[0][off];
        float4 a1 = *(float4*)&accS[1][off];
        float4 a2 = *(float4*)&accS[2][off];
        float4 a3 = *(float4*)&accS[3][off];
        float inv = 1.f / ls;
        ushort4 o;
        o.x = f2b((a0.x*e0 + a1.x*e1 + a2.x*e2 + a3.x*e3) * inv);
        o.y = f2b((a0.y*e0 + a1.y*e1 + a2.y*e2 + a3.y*e3) * inv);
        o.z = f2b((a0.z*e0 + a1.z*e1 + a2.z*e2 + a3.z*e3) * inv);
        o.w = f2b((a0.w*e0 + a1.w*e1 + a2.w*e2 + a3.w*e3) * inv);
        *(ushort4*)(ctxb + (size_t)i*HIDN + off) = o;
    }
}

template<bool RES>
__device__ __forceinline__ void d_ln(int row, float* x, const float* r,
    const float* g, const float* b, unsigned short* xb, float (&red)[4])
{
    __syncthreads();
    int c = threadIdx.x;
    float v = x[(size_t)row*HIDN + c];
    if (RES) v += r[(size_t)row*HIDN + c];
    float s = v;
    for (int mm = 1; mm < 64; mm <<= 1) s += __shfl_xor(s, mm);
    if ((c & 63) == 0) red[c >> 6] = s;
    __syncthreads();
    float mean = (red[0] + red[1] + red[2] + red[3]) * (1.f / HIDN);
    __syncthreads();
    float dv = v - mean;
    float qq = dv * dv;
    for (int mm = 1; mm < 64; mm <<= 1) qq += __shfl_xor(qq, mm);
    if ((c & 63) == 0) red[c >> 6] = qq;
    __syncthreads();
    float var = (red[0] + red[1] + red[2] + red[3]) * (1.f / HIDN);
    float rs = rsqrtf(var + 1e-5f);
    float o = dv * rs * g[c] + b[c];
    x[(size_t)row*HIDN + c] = o;
    xb[(size_t)row*HIDN + c] = f2b(o);
}

// 4-layer transformer in one cooperative kernel. 512 blocks @ 2/CU (safe).
__global__ __launch_bounds__(256, 2)
void megakernel(MegaArgs a)
{
    cg::grid_group grid = cg::this_grid();
    __shared__ __align__(16) unsigned short As[2][32*40];
    __shared__ __align__(16) unsigned short Bs[2][64*40];
    __shared__ float mS[4][8], lS[4][8];
    __shared__ __align__(16) float accS[4][256];
    __shared__ float red[4];
    int bid = blockIdx.x;
    for (int l = 0; l < NLAYER; l++) {
        // ---- QKV: 768 tiles (12 x 64) ----
        d_mgemm<256,0,1>(bid % 12, bid / 12, a.xb, a.WqkvT + (size_t)l*768*HIDN,
                         a.bqkv + l*768, nullptr, a.bufQKVb, 768, As, Bs);
        if (bid < 256) {
            int t2 = bid + 512;
            d_mgemm<256,0,1>(t2 % 12, t2 / 12, a.xb, a.WqkvT + (size_t)l*768*HIDN,
                             a.bqkv + l*768, nullptr, a.bufQKVb, 768, As, Bs);
        }
        grid.sync();
        // ---- attention: 4 nodes per block ----
        d_attn(bid,        a.bufQKVb, a.rowoff, a.cols, a.bias_csr, a.bufAb, l, mS, lS, accS);
        d_attn(bid + 512,  a.bufQKVb, a.rowoff, a.cols, a.bias_csr, a.bufAb, l, mS, lS, accS);
        d_attn(bid + 1024, a.bufQKVb, a.rowoff, a.cols, a.bias_csr, a.bufAb, l, mS, lS, accS);
        d_attn(bid + 1536, a.bufQKVb, a.rowoff, a.cols, a.bias_csr, a.bufAb, l, mS, lS, accS);
        grid.sync();
        // ---- O-proj: 256 tiles (4 x 64) ----
        if (bid < 256)
            d_mgemm<256,0,0>(bid % 4, bid / 4, a.bufAb, a.WoT + (size_t)l*HIDN*HIDN,
                             a.bo + l*HIDN, a.bufO, nullptr, 256, As, Bs);
        grid.sync();
        // ---- LN1: 4 rows per block ----
        d_ln<true>(4*bid,     a.x, a.bufO, a.g1 + l*HIDN, a.be1 + l*HIDN, a.xb, red);
        d_ln<true>(4*bid + 1, a.x, a.bufO, a.g1 + l*HIDN, a.be1 + l*HIDN, a.xb, red);
        d_ln<true>(4*bid + 2, a.x, a.bufO, a.g1 + l*HIDN, a.be1 + l*HIDN, a.xb, red);
        d_ln<true>(4*bid + 3, a.x, a.bufO, a.g1 + l*HIDN, a.be1 + l*HIDN, a.xb, red);
        grid.sync();
        // ---- FF1: 1024 tiles (16 x 64) ----
        d_mgemm<256,1,1>(bid % 16, bid / 16, a.xb, a.Wf1T + (size_t)l*FFD*HIDN,
                         a.bf1 + l*FFD, nullptr, a.bufFb, 1024, As, Bs);
        {
            int t2 = bid + 512;
            d_mgemm<256,1,1>(t2 % 16, t2 / 16, a.xb, a.Wf1T + (size_t)l*FFD*HIDN,
                             a.bf1 + l*FFD, nullptr, a.bufFb, 1024, As, Bs);
        }
        grid.sync();
        // ---- FF2: 256 tiles (4 x 64) ----
        if (bid < 256)
            d_mgemm<1024,0,0>(bid % 4, bid / 4, a.bufFb, a.Wf2T + (size_t)l*HIDN*FFD,
                              a.bf2 + l*HIDN, a.bufO, nullptr, 256, As, Bs);
        grid.sync();
        // ---- LN2 ----
        d_ln<true>(4*bid,     a.x, a.bufO, a.g2 + l*HIDN, a.be2 + l*HIDN, a.xb, red);
        d_ln<true>(4*bid + 1, a.x, a.bufO, a.g2 + l*HIDN, a.be2 + l*HIDN, a.xb, red);
        d_ln<true>(4*bid + 2, a.x, a.bufO, a.g2 + l*HIDN, a.be2 + l*HIDN, a.xb, red);
        d_ln<true>(4*bid + 3, a.x, a.bufO, a.g2 + l*HIDN, a.be2 + l*HIDN, a.xb, red);
        if (l < NLAYER - 1) grid.sync();
    }
    // ---- final LN: same rows as this block's LN2 -> no grid sync needed ----
    d_ln<false>(4*bid,     a.x, nullptr, a.g_ln, a.b_ln, a.xb, red);
    d_ln<false>(4*bid + 1, a.x, nullptr, a.g_ln, a.b_ln, a.xb, red);
    d_ln<false>(4*bid + 2, a.x, nullptr, a.g_ln, a.b_ln, a.xb, red);
    d_ln<false>(4*bid + 3, a.x, nullptr, a.g_ln, a.b_ln, a.xb, red);
}

// ----------------------------- fallback standalone kernels (R9-proven) ----
__global__ __launch_bounds__(256)
void attn_kernel(const unsigned short* __restrict__ QKVb, const int* __restrict__ rowoff,
                 const int* __restrict__ cols, const float* __restrict__ bias_csr,
                 unsigned short* __restrict__ ctxb, int layer)
{
    __shared__ float mS[4][8], lS[4][8];
    __shared__ __align__(16) float accS[4][256];
    d_attn(blockIdx.x, QKVb, rowoff, cols, bias_csr, ctxb, layer, mS, lS, accS);
}

template<bool RES>
__global__ __launch_bounds__(256)
void ln_kernel(float* __restrict__ x, const float* __restrict__ r,
               const float* __restrict__ g, const float* __restrict__ b,
               unsigned short* __restrict__ xb)
{
    __shared__ float red[4];
    d_ln<RES>(blockIdx.x, x, r, g, b, xb, red);
}

// ------------------------------------------------- weight prep (per call) --
__global__ __launch_bounds__(256)
void transpose_all(const float* __restrict__ Wq, const float* __restrict__ Wk,
                   const float* __restrict__ Wv, const float* __restrict__ Wo,
                   const float* __restrict__ Wf1, const float* __restrict__ Wf2,
                   const float* __restrict__ W_node, const float* __restrict__ Wp1,
                   unsigned short* __restrict__ WqkvT, unsigned short* __restrict__ WoT,
                   unsigned short* __restrict__ Wf1T, unsigned short* __restrict__ Wf2T,
                   unsigned short* __restrict__ WnT, unsigned short* __restrict__ Wp1T,
                   const float* __restrict__ nf, unsigned short* __restrict__ nf_b,
                   const float* __restrict__ bq, const float* __restrict__ bk,
                   const float* __restrict__ bv, float* __restrict__ bqkv)
{
    __shared__ unsigned short tile[32][33];
    int bid = blockIdx.x;
    if (bid >= 3168) {
        int t = (bid - 3168) * 256 + threadIdx.x;
        if (t < NNODE*128) {
            nf_b[t] = f2b(nf[t]);
        } else {
            int u = t - NNODE*128;
            if (u < NLAYER*768) {
                int l = u / 768, j = u % 768;
                float vv = (j < 256) ? bq[l*256 + j] : (j < 512 ? bk[l*256 + j - 256] : bv[l*256 + j - 512]);
                bqkv[u] = vv;
            }
        }
        return;
    }
    const float* s; unsigned short* d; int K, N, n0, k0;
    if (bid < 1024) {
        int mat = bid >> 6, rem = bid & 63;
        int m4 = mat & 3, l = mat >> 2;
        s = (m4 == 0 ? Wq : m4 == 1 ? Wk : m4 == 2 ? Wv : Wo) + (size_t)l * 65536;
        d = (m4 < 3) ? WqkvT + (size_t)l*196608 + (size_t)m4*65536
                     : WoT + (size_t)l*65536;
        K = 256; N = 256; n0 = (rem & 7) * 32; k0 = (rem >> 3) * 32;
    } else if (bid < 2048) {
        int idx = bid - 1024; int l = idx >> 8, rem = idx & 255;
        s = Wf1 + (size_t)l*262144; d = Wf1T + (size_t)l*262144;
        K = 256; N = 1024; n0 = (rem & 31) * 32; k0 = (rem >> 5) * 32;
    } else if (bid < 3072) {
        int idx = bid - 2048; int l = idx >> 8, rem = idx & 255;
        s = Wf2 + (size_t)l*262144; d = Wf2T + (size_t)l*262144;
        K = 1024; N = 256; n0 = (rem & 7) * 32; k0 = (rem >> 3) * 32;
    } else if (bid < 3104) {
        int rem = bid - 3072;
        s = W_node; d = WnT;
        K = 128; N = 256; n0 = (rem & 7) * 32; k0 = (rem >> 3) * 32;
    } else {
        int rem = bid - 3104;
        s = Wp1; d = Wp1T;
        K = 256; N = 256; n0 = (rem & 7) * 32; k0 = (rem >> 3) * 32;
    }
    int tx = threadIdx.x & 31, ty = threadIdx.x >> 5;
    #pragma unroll
    for (int i = 0; i < 4; i++)
        tile[ty + i*8][tx] = f2b(s[(size_t)(k0 + ty + i*8) * N + n0 + tx]);
    __syncthreads();
    #pragma unroll
    for (int i = 0; i < 4; i++)
        d[(size_t)(n0 + ty + i*8) * K + k0 + tx] = tile[tx][ty + i*8];
}

// ------------------------------------------------------- adjacency / CSR ---
__global__ void adj_build(const int* __restrict__ src, const int* __restrict__ dst,
                          unsigned* __restrict__ adjbits)
{
    int t = blockIdx.x * blockDim.x + threadIdx.x;
    if (t < NEDGE) {
        int s = src[t], d = dst[t];
        atomicOr(&adjbits[(size_t)s*64 + (d >> 5)], 1u << (d & 31));
        atomicOr(&adjbits[(size_t)d*64 + (s >> 5)], 1u << (s & 31));
    }
    if (t < NNODE)
        atomicOr(&adjbits[(size_t)t*64 + (t >> 5)], 1u << (t & 31));
}

__global__ void row_rank(const unsigned* __restrict__ adjbits,
                         unsigned* __restrict__ rowcum, int* __restrict__ deg)
{
    int i = blockIdx.x * blockDim.x + threadIdx.x;
    if (i >= NNODE) return;
    unsigned c = 0;
    for (int w = 0; w < 64; w++) {
        rowcum[i*64 + w] = c;
        c += __popc(adjbits[i*64 + w]);
    }
    deg[i] = (int)c;
}

__global__ __launch_bounds__(256)
void scan_kernel(const int* __restrict__ deg, int* __restrict__ rowoff)
{
    __shared__ int part[256];
    int tid = threadIdx.x;
    int base = tid * 8;
    int local[8]; int s = 0;
    #pragma unroll
    for (int k = 0; k < 8; k++) { local[k] = s; s += deg[base + k]; }
    part[tid] = s;
    __syncthreads();
    for (int off = 1; off < 256; off <<= 1) {
        int v = (tid >= off) ? part[tid - off] : 0;
        __syncthreads();
        part[tid] += v;
        __syncthreads();
    }
    int pre = (tid == 0) ? 0 : part[tid - 1];
    #pragma unroll
    for (int k = 0; k < 8; k++) rowoff[base + k] = pre + local[k];
    if (tid == 255) rowoff[NNODE] = part[255];
}

__global__ __launch_bounds__(256)
void fill_cols(const unsigned* __restrict__ adjbits, const int* __restrict__ rowoff,
               const unsigned* __restrict__ rowcum, int* __restrict__ cols)
{
    int t = blockIdx.x * 256 + threadIdx.x;
    int i = t >> 6, w = t & 63;
    unsigned bits = adjbits[(size_t)i*64 + w];
    int base = rowoff[i] + (int)rowcum[(size_t)i*64 + w];
    while (bits) {
        int b = __ffs(bits) - 1;
        cols[base++] = w*32 + b;
        bits &= bits - 1;
    }
}

__global__ void wcomb_kernel(const float* __restrict__ W_edge, const float* __restrict__ b_edge,
                             const float* __restrict__ Wep, const float* __restrict__ bep,
                             float* __restrict__ Wcomb, float* __restrict__ bcomb)
{
    int t = blockIdx.x * blockDim.x + threadIdx.x;
    if (t < 64*32) {
        int k = t >> 5, lh = t & 31, l = lh >> 3, h = lh & 7;
        float acc = 0.f;
        for (int c = 0; c < HIDN; c++)
            acc += W_edge[k*HIDN + c] * Wep[l*HIDN*NHEAD + c*NHEAD + h];
        Wcomb[k*32 + lh] = acc;
    } else if (t < 64*32 + 32) {
        int lh = t - 64*32, l = lh >> 3, h = lh & 7;
        float acc = bep[l*NHEAD + h];
        for (int c = 0; c < HIDN; c++)
            acc += b_edge[c] * Wep[l*HIDN*NHEAD + c*NHEAD + h];
        bcomb[lh] = acc;
    }
}

__global__ __launch_bounds__(256)
void edge_bias_scatter(const float* __restrict__ ef, const float* __restrict__ Wcomb,
                       const float* __restrict__ bcomb,
                       const int* __restrict__ src, const int* __restrict__ dst,
                       const unsigned* __restrict__ adjbits,
                       const unsigned* __restrict__ rowcum,
                       const int* __restrict__ rowoff, float* __restrict__ bias_csr)
{
    __shared__ float Wl[64*32];
    __shared__ float bl[32];
    int tid = threadIdx.x;
    for (int k = tid; k < 64*32; k += 256) Wl[k] = Wcomb[k];
    if (tid < 32) bl[tid] = bcomb[tid];
    __syncthreads();
    int t = blockIdx.x * 256 + tid;
    int e = t >> 5, lh = t & 31;
    const float* f = ef + (size_t)e * 64;
    float acc = bl[lh];
    #pragma unroll
    for (int k = 0; k < 64; k++) acc += f[k] * Wl[k*32 + lh];
    int s = src[e], d = dst[e];
    unsigned wbits = adjbits[(size_t)s*64 + (d >> 5)];
    int rank = (int)rowcum[(size_t)s*64 + (d >> 5)] + __popc(wbits & ((1u << (d & 31)) - 1u));
    int slot = rowoff[s] + rank;
    atomicAdd(&bias_csr[(size_t)slot*32 + lh], acc);
}

// ----------------------------------------- pooling: 16-block partials ------
__global__ __launch_bounds__(256)
void pool_part(const float* __restrict__ x, const float* __restrict__ sred,
               float* __restrict__ partial)
{
    __shared__ float red[4];
    __shared__ float aw[128];
    int b = blockIdx.x, tid = threadIdx.x;
    float mxs = -INFINITY;
    for (int r = tid; r < NNODE; r += 256) mxs = fmaxf(mxs, sred[r]);
    for (int mm = 1; mm < 64; mm <<= 1) mxs = fmaxf(mxs, __shfl_xor(mxs, mm));
    if ((tid & 63) == 0) red[tid >> 6] = mxs;
    __syncthreads();
    mxs = fmaxf(fmaxf(red[0], red[1]), fmaxf(red[2], red[3]));
    __syncthreads();
    float ss = 0.f;
    for (int r = tid; r < NNODE; r += 256) ss += __expf(sred[r] - mxs);
    for (int mm = 1; mm < 64; mm <<= 1) ss += __shfl_xor(ss, mm);
    if ((tid & 63) == 0) red[tid >> 6] = ss;
    __syncthreads();
    ss = red[0] + red[1] + red[2] + red[3];
    float inv = 1.f / ss;
    int r0 = b * 128;
    if (tid < 128) aw[tid] = __expf(sred[r0 + tid] - mxs) * inv;
    __syncthreads();
    float sm = 0.f, mx = -INFINITY, ap = 0.f;
    for (int r = 0; r < 128; r++) {
        float v = x[(size_t)(r0 + r)*HIDN + tid];
        sm += v;
        mx = fmaxf(mx, v);
        ap += v * aw[r];
    }
    partial[(size_t)b*768 + tid]       = sm;
    partial[(size_t)b*768 + 256 + tid] = mx;
    partial[(size_t)b*768 + 512 + tid] = ap;
}

__global__ __launch_bounds__(256)
void pool_fin(const float* __restrict__ partial, float* __restrict__ g)
{
    int c = threadIdx.x;
    float sm = 0.f, mx = -INFINITY, ap = 0.f;
    for (int b = 0; b < 16; b++) {
        sm += partial[(size_t)b*768 + c];
        mx = fmaxf(mx, partial[(size_t)b*768 + 256 + c]);
        ap += partial[(size_t)b*768 + 512 + c];
    }
    g[c]          = sm * (1.f / NNODE);
    g[HIDN + c]   = mx;
    g[2*HIDN + c] = ap;
}

// --------------------------------------------------------------- head ------
__global__ __launch_bounds__(256)
void head1(const float* __restrict__ g, const float* __restrict__ Wo1,
           const float* __restrict__ bo1, float* __restrict__ h1)
{
    __shared__ float hp[4][64];
    int tid = threadIdx.x;
    int w = tid >> 6, lane = tid & 63;
    int j = blockIdx.x * 64 + lane;
    float acc = 0.f;
    int k0 = w * 192;
    for (int k = k0; k < k0 + 192; k++)
        acc += g[k] * Wo1[(size_t)k*512 + j];
    hp[w][lane] = acc;
    __syncthreads();
    if (w == 0) {
        float s = hp[0][lane] + hp[1][lane] + hp[2][lane] + hp[3][lane] + bo1[j];
        h1[j] = fmaxf(s, 0.f);
    }
}

__global__ __launch_bounds__(256)
void head2(const float* __restrict__ h1, const float* __restrict__ Wo2,
           const float* __restrict__ bo2, float* __restrict__ out)
{
    __shared__ float hp[4][64];
    int tid = threadIdx.x;
    int w = tid >> 6, lane = tid & 63;
    int j = blockIdx.x * 64 + lane;
    float acc = 0.f;
    int k0 = w * 128;
    for (int k = k0; k < k0 + 128; k++)
        acc += h1[k] * Wo2[(size_t)k*OUTD + j];
    hp[w][lane] = acc;
    __syncthreads();
    if (w == 0)
        out[j] = hp[0][lane] + hp[1][lane] + hp[2][lane] + hp[3][lane] + bo2[j];
}

// ------------------------------------------------------------- launch ------
extern "C" void kernel_launch(void* const* d_in, const int* in_sizes, int n_in,
                              void* d_out, int out_size, void* d_ws, size_t ws_size,
                              hipStream_t stream)
{
    const float* node_features = (const float*)d_in[0];
    const float* edge_features = (const float*)d_in[1];
    const int*   edge_index    = (const int*)d_in[2];
    const float* W_node = (const float*)d_in[3];
    const float* b_node = (const float*)d_in[4];
    const float* W_edge = (const float*)d_in[5];
    const float* b_edge = (const float*)d_in[6];
    const float* pos_emb = (const float*)d_in[7];
    const float* Wq = (const float*)d_in[8];
    const float* bq = (const float*)d_in[9];
    const float* Wk = (const float*)d_in[10];
    const float* bk = (const float*)d_in[11];
    const float* Wv = (const float*)d_in[12];
    const float* bv = (const float*)d_in[13];
    const float* Wo = (const float*)d_in[14];
    const float* bo = (const float*)d_in[15];
    const float* Wep = (const float*)d_in[16];
    const float* bep = (const float*)d_in[17];
    const float* Wf1 = (const float*)d_in[18];
    const float* bf1 = (const float*)d_in[19];
    const float* Wf2 = (const float*)d_in[20];
    const float* bf2 = (const float*)d_in[21];
    const float* g1  = (const float*)d_in[22];
    const float* be1 = (const float*)d_in[23];
    const float* g2  = (const float*)d_in[24];
    const float* be2 = (const float*)d_in[25];
    const float* g_ln = (const float*)d_in[26];
    const float* b_ln = (const float*)d_in[27];
    const float* Wp1 = (const float*)d_in[28];
    const float* bp1 = (const float*)d_in[29];
    const float* Wp2 = (const float*)d_in[30];
    const float* bp2 = (const float*)d_in[31];
    const float* Wo1 = (const float*)d_in[32];
    const float* bo1 = (const float*)d_in[33];
    const float* Wo2 = (const float*)d_in[34];
    const float* bo2 = (const float*)d_in[35];
    (void)bp2;
    const int* src = edge_index;
    const int* dst = edge_index + NEDGE;

    char* w = (char*)d_ws;
    auto carve = [&](size_t nbytes) {
        void* p = (void*)w;
        w += (nbytes + 255) & ~(size_t)255;
        return p;
    };
    float* x        = (float*)carve((size_t)NNODE*HIDN*4);
    unsigned short* xb = (unsigned short*)carve((size_t)NNODE*HIDN*2);
    unsigned short* bufQKVb = (unsigned short*)carve((size_t)NNODE*768*2);
    float* bufO     = (float*)carve((size_t)NNODE*HIDN*4);
    unsigned short* bufAb = (unsigned short*)carve((size_t)NNODE*HIDN*2);
    unsigned short* bufFb = (unsigned short*)carve((size_t)NNODE*FFD*2);
    float* Wcomb    = (float*)carve(64*32*4);
    float* bcomb    = (float*)carve(32*4);
    unsigned* adjbits = (unsigned*)carve((size_t)NNODE*64*4);
    float* bias_csr = (float*)carve((size_t)NNZ_MAX*32*4);
    float* sbuf  = (float*)carve(NNODE*4);
    unsigned* rowcum  = (unsigned*)carve((size_t)NNODE*64*4);
    int* deg    = (int*)carve(NNODE*4);
    int* rowoff = (int*)carve((NNODE+1)*4);
    int* colsb  = (int*)carve((size_t)NNZ_MAX*4);
    float* gbuf  = (float*)carve(3*HIDN*4);
    float* partial = (float*)carve(16*768*4);
    float* h1buf = (float*)carve(512*4);
    unsigned short* nf_b  = (unsigned short*)carve((size_t)NNODE*128*2);
    unsigned short* WnT   = (unsigned short*)carve((size_t)HIDN*128*2);
    unsigned short* WqkvT = (unsigned short*)carve((size_t)NLAYER*768*HIDN*2);
    float*          bqkv  = (float*)carve((size_t)NLAYER*768*4);
    unsigned short* WoT   = (unsigned short*)carve((size_t)NLAYER*HIDN*HIDN*2);
    unsigned short* Wf1T  = (unsigned short*)carve((size_t)NLAYER*FFD*HIDN*2);
    unsigned short* Wf2T  = (unsigned short*)carve((size_t)NLAYER*HIDN*FFD*2);
    unsigned short* Wp1T  = (unsigned short*)carve((size_t)HIDN*HIDN*2);

    // ---- zero adjbits + bias_csr + sbuf in one shot ----
    hipMemsetAsync(adjbits, 0,
                   (size_t)NNODE*64*4 + (size_t)NNZ_MAX*32*4 + (size_t)NNODE*4, stream);
    adj_build<<<(NEDGE+255)/256, 256, 0, stream>>>(src, dst, adjbits);
    row_rank<<<NNODE/256, 256, 0, stream>>>(adjbits, rowcum, deg);
    scan_kernel<<<1, 256, 0, stream>>>(deg, rowoff);
    fill_cols<<<(NNODE*64)/256, 256, 0, stream>>>(adjbits, rowoff, rowcum, colsb);
    wcomb_kernel<<<(64*32+32+255)/256, 256, 0, stream>>>(W_edge, b_edge, Wep, bep, Wcomb, bcomb);
    edge_bias_scatter<<<(NEDGE*32)/256, 256, 0, stream>>>(
        edge_features, Wcomb, bcomb, src, dst, adjbits, rowcum, rowoff, bias_csr);

    // ---- weight prep ----
    transpose_all<<<3168 + 1024 + 12, 256, 0, stream>>>(
        Wq, Wk, Wv, Wo, Wf1, Wf2, W_node, Wp1,
        WqkvT, WoT, Wf1T, Wf2T, WnT, Wp1T,
        node_features, nf_b, bq, bk, bv, bqkv);

    // ---- node encoding: x = nf @ W_node + b_node + pos_emb ----
    mgemm<128,3,2><<<dim3(HIDN/64, NNODE/32), 256, 0, stream>>>(
        nf_b, WnT, b_node, pos_emb, x, xb, NNODE, HIDN, nullptr, nullptr);

    // ---- transformer stack: cooperative megakernel, R9 fallback on error ----
    MegaArgs margs;
    margs.x = x; margs.xb = xb;
    margs.bufQKVb = bufQKVb; margs.bufAb = bufAb;
    margs.bufO = bufO; margs.bufFb = bufFb;
    margs.WqkvT = WqkvT; margs.WoT = WoT; margs.Wf1T = Wf1T; margs.Wf2T = Wf2T;
    margs.bqkv = bqkv; margs.bo = bo; margs.bf1 = bf1; margs.bf2 = bf2;
    margs.g1 = g1; margs.be1 = be1; margs.g2 = g2; margs.be2 = be2;
    margs.g_ln = g_ln; margs.b_ln = b_ln;
    margs.rowoff = rowoff; margs.cols = colsb; margs.bias_csr = bias_csr;
    void* kargs[] = { &margs };
    hipError_t cerr = hipLaunchCooperativeKernel((const void*)megakernel, dim3(512),
                                                 dim3(256), kargs, 0, stream);
    if (cerr != hipSuccess) {
        (void)hipGetLastError();   // clear sticky error
        for (int l = 0; l < NLAYER; l++) {
            mgemm<256,0,1><<<dim3(768/64, NNODE/32), 256, 0, stream>>>(
                xb, WqkvT + (size_t)l*768*HIDN, bqkv + l*768, nullptr, nullptr, bufQKVb, NNODE, 768, nullptr, nullptr);
            attn_kernel<<<NNODE, 256, 0, stream>>>(bufQKVb, rowoff, colsb, bias_csr, bufAb, l);
            mgemm<256,0,0><<<dim3(HIDN/64, NNODE/32), 256, 0, stream>>>(
                bufAb, WoT + (size_t)l*HIDN*HIDN, bo + l*HIDN, nullptr, bufO, nullptr, NNODE, HIDN, nullptr, nullptr);
            ln_kernel<true><<<NNODE, 256, 0, stream>>>(x, bufO, g1 + l*HIDN, be1 + l*HIDN, xb);
            mgemm<256,1,1><<<dim3(FFD/64, NNODE/32), 256, 0, stream>>>(
                xb, Wf1T + (size_t)l*FFD*HIDN, bf1 + l*FFD, nullptr, nullptr, bufFb, NNODE, FFD, nullptr, nullptr);
            mgemm<1024,0,0><<<dim3(HIDN/64, NNODE/32), 256, 0, stream>>>(
                bufFb, Wf2T + (size_t)l*HIDN*FFD, bf2 + l*HIDN, nullptr, bufO, nullptr, NNODE, HIDN, nullptr, nullptr);
            ln_kernel<true><<<NNODE, 256, 0, stream>>>(x, bufO, g2 + l*HIDN, be2 + l*HIDN, xb);
        }
        ln_kernel<false><<<NNODE, 256, 0, stream>>>(x, nullptr, g_ln, b_ln, xb);
    }

    // ---- pooling (Wp1 GEMM fused with score reduce) + head ----
    mgemm<256,4,0><<<dim3(HIDN/64, NNODE/32), 256, 0, stream>>>(
        xb, Wp1T, bp1, nullptr, nullptr, nullptr, NNODE, HIDN, Wp2, sbuf);
    pool_part<<<16, 256, 0, stream>>>(x, sbuf, partial);
    pool_fin<<<1, 256, 0, stream>>>(partial, gbuf);
    head1<<<8, 256, 0, stream>>>(gbuf, Wo1, bo1, h1buf);
    head2<<<OUTD/64, 256, 0, stream>>>(h1buf, Wo2, bo2, (float*)d_out);
}

// Round 14
// 453.043 us; speedup vs baseline: 4.7201x; 4.7201x over previous
//
#include <hip/hip_runtime.h>
#include <math.h>

#define NNODE 2048
#define NEDGE 65536
#define HIDN  256
#define NHEAD 8
#define HDIM  32
#define FFD   1024
#define NLAYER 4
#define OUTD  1280
#define NNZ_MAX (2*NEDGE + NNODE)

typedef __attribute__((ext_vector_type(8))) short bf16x8;
typedef __attribute__((ext_vector_type(4))) float f32x4;

__device__ __forceinline__ unsigned short f2b(float f) {
    unsigned u = __float_as_uint(f);
    unsigned r = (u + 0x7fffu + ((u >> 16) & 1u)) >> 16;
    return (unsigned short)r;
}
__device__ __forceinline__ float b2f(unsigned short u) {
    return __uint_as_float((unsigned)u << 16);
}

// ----------------------------------------------------------- MFMA GEMM -----
// C[M,N] = A[M,K] @ Bt[N,K]^T + bias. 32x64 tile, BK=32, LDS double-buffer +
// register prefetch (R9-proven best config).
// EPI: 0=bias, 1=bias+gelu, 3=bias+extra, 4=tanh+pool-reduce(Wp2->sred)
// OUT: 0=fp32 Cf, 1=bf16 Cb, 2=both
template<int K, int EPI, int OUT>
__global__ __launch_bounds__(256)
void mgemm(const unsigned short* __restrict__ A, const unsigned short* __restrict__ Bt,
           const float* __restrict__ bias, const float* __restrict__ extra,
           float* __restrict__ Cf, unsigned short* __restrict__ Cb,
           int M, int N, const float* __restrict__ Wp2, float* __restrict__ sred)
{
    __shared__ __align__(16) unsigned short As[2][32 * 40];
    __shared__ __align__(16) unsigned short Bs[2][64 * 40];
    int tid = threadIdx.x;
    int bm0 = blockIdx.y * 32, bn0 = blockIdx.x * 64;
    int wave = tid >> 6, lane = tid & 63;
    int wm = (wave >> 1) * 16;
    int wn = (wave & 1) * 32;
    int lrow = lane & 15, quad = lane >> 4;
    int brow = tid >> 2, koff = (tid & 3) * 8;
    int arow = (tid & 127) >> 2;
    bool doA = tid < 128;
    const unsigned short* ap = A  + (size_t)(bm0 + arow) * K + koff;
    const unsigned short* bp = Bt + (size_t)(bn0 + brow) * K + koff;
    uint4 av, bv;
    if (doA) av = *(const uint4*)ap;
    bv = *(const uint4*)bp;
    constexpr int NC = K / 32;
    if (doA) *(uint4*)(&As[0][arow*40 + koff]) = av;
    *(uint4*)(&Bs[0][brow*40 + koff]) = bv;
    __syncthreads();
    f32x4 acc[2] = {};
    #pragma unroll 8
    for (int c = 0; c < NC; ++c) {
        int cur = c & 1;
        if (c + 1 < NC) {
            if (doA) av = *(const uint4*)(ap + (c+1)*32);
            bv = *(const uint4*)(bp + (c+1)*32);
        }
        bf16x8 af = *(const bf16x8*)(&As[cur][(wm + lrow)*40 + quad*8]);
        bf16x8 b0 = *(const bf16x8*)(&Bs[cur][(wn + lrow)*40 + quad*8]);
        bf16x8 b1 = *(const bf16x8*)(&Bs[cur][(wn + 16 + lrow)*40 + quad*8]);
        acc[0] = __builtin_amdgcn_mfma_f32_16x16x32_bf16(af, b0, acc[0], 0, 0, 0);
        acc[1] = __builtin_amdgcn_mfma_f32_16x16x32_bf16(af, b1, acc[1], 0, 0, 0);
        if (c + 1 < NC) {
            if (doA) *(uint4*)(&As[cur^1][arow*40 + koff]) = av;
            *(uint4*)(&Bs[cur^1][brow*40 + koff]) = bv;
        }
        __syncthreads();
    }
    if (EPI == 4) {
        #pragma unroll
        for (int r = 0; r < 4; r++) {
            int row = bm0 + wm + quad*4 + r;
            float ps = 0.f;
            #pragma unroll
            for (int j = 0; j < 2; j++) {
                int col = bn0 + wn + j*16 + lrow;
                float v = tanhf(acc[j][r] + bias[col]);
                ps += v * Wp2[col];
            }
            ps += __shfl_xor(ps, 1);
            ps += __shfl_xor(ps, 2);
            ps += __shfl_xor(ps, 4);
            ps += __shfl_xor(ps, 8);
            if (lrow == 0) atomicAdd(&sred[row], ps);
        }
        return;
    }
    #pragma unroll
    for (int j = 0; j < 2; j++) {
        int col = bn0 + wn + j*16 + lrow;
        float bvv = bias[col];
        #pragma unroll
        for (int r = 0; r < 4; r++) {
            int row = bm0 + wm + quad*4 + r;
            float v = acc[j][r] + bvv;
            if (EPI == 1) v = 0.5f * v * (1.f + erff(v * 0.70710678118654752f));
            else if (EPI == 3) v += extra[(size_t)row*N + col];
            if (OUT == 0 || OUT == 2) Cf[(size_t)row*N + col] = v;
            if (OUT == 1 || OUT == 2) Cb[(size_t)row*N + col] = f2b(v);
        }
    }
}

// ------------------------------------------------- weight prep (per call) --
// Weight transposes + nf convert + bias concat + Wcomb build in ONE launch.
__global__ __launch_bounds__(256)
void transpose_all(const float* __restrict__ Wq, const float* __restrict__ Wk,
                   const float* __restrict__ Wv, const float* __restrict__ Wo,
                   const float* __restrict__ Wf1, const float* __restrict__ Wf2,
                   const float* __restrict__ W_node, const float* __restrict__ Wp1,
                   unsigned short* __restrict__ WqkvT, unsigned short* __restrict__ WoT,
                   unsigned short* __restrict__ Wf1T, unsigned short* __restrict__ Wf2T,
                   unsigned short* __restrict__ WnT, unsigned short* __restrict__ Wp1T,
                   const float* __restrict__ nf, unsigned short* __restrict__ nf_b,
                   const float* __restrict__ bq, const float* __restrict__ bk,
                   const float* __restrict__ bv, float* __restrict__ bqkv,
                   const float* __restrict__ W_edge, const float* __restrict__ b_edge,
                   const float* __restrict__ Wep, const float* __restrict__ bep,
                   float* __restrict__ Wcomb, float* __restrict__ bcomb)
{
    __shared__ unsigned short tile[32][33];
    int bid = blockIdx.x;
    if (bid >= 4204) {   // wcomb range: combined edge-bias weights
        int t = (bid - 4204) * 256 + threadIdx.x;
        if (t < 64*32) {
            int k = t >> 5, lh = t & 31, l = lh >> 3, h = lh & 7;
            float acc = 0.f;
            for (int c = 0; c < HIDN; c++)
                acc += W_edge[k*HIDN + c] * Wep[l*HIDN*NHEAD + c*NHEAD + h];
            Wcomb[k*32 + lh] = acc;
        } else if (t < 64*32 + 32) {
            int lh = t - 64*32, l = lh >> 3, h = lh & 7;
            float acc = bep[l*NHEAD + h];
            for (int c = 0; c < HIDN; c++)
                acc += b_edge[c] * Wep[l*HIDN*NHEAD + c*NHEAD + h];
            bcomb[lh] = acc;
        }
        return;
    }
    if (bid >= 3168) {   // misc: nf bf16 convert + qkv bias concat
        int t = (bid - 3168) * 256 + threadIdx.x;
        if (t < NNODE*128) {
            nf_b[t] = f2b(nf[t]);
        } else {
            int u = t - NNODE*128;
            if (u < NLAYER*768) {
                int l = u / 768, j = u % 768;
                float vv = (j < 256) ? bq[l*256 + j] : (j < 512 ? bk[l*256 + j - 256] : bv[l*256 + j - 512]);
                bqkv[u] = vv;
            }
        }
        return;
    }
    const float* s; unsigned short* d; int K, N, n0, k0;
    if (bid < 1024) {
        int mat = bid >> 6, rem = bid & 63;
        int m4 = mat & 3, l = mat >> 2;
        s = (m4 == 0 ? Wq : m4 == 1 ? Wk : m4 == 2 ? Wv : Wo) + (size_t)l * 65536;
        d = (m4 < 3) ? WqkvT + (size_t)l*196608 + (size_t)m4*65536
                     : WoT + (size_t)l*65536;
        K = 256; N = 256; n0 = (rem & 7) * 32; k0 = (rem >> 3) * 32;
    } else if (bid < 2048) {
        int idx = bid - 1024; int l = idx >> 8, rem = idx & 255;
        s = Wf1 + (size_t)l*262144; d = Wf1T + (size_t)l*262144;
        K = 256; N = 1024; n0 = (rem & 31) * 32; k0 = (rem >> 5) * 32;
    } else if (bid < 3072) {
        int idx = bid - 2048; int l = idx >> 8, rem = idx & 255;
        s = Wf2 + (size_t)l*262144; d = Wf2T + (size_t)l*262144;
        K = 1024; N = 256; n0 = (rem & 7) * 32; k0 = (rem >> 3) * 32;
    } else if (bid < 3104) {
        int rem = bid - 3072;
        s = W_node; d = WnT;
        K = 128; N = 256; n0 = (rem & 7) * 32; k0 = (rem >> 3) * 32;
    } else {
        int rem = bid - 3104;
        s = Wp1; d = Wp1T;
        K = 256; N = 256; n0 = (rem & 7) * 32; k0 = (rem >> 3) * 32;
    }
    int tx = threadIdx.x & 31, ty = threadIdx.x >> 5;
    #pragma unroll
    for (int i = 0; i < 4; i++)
        tile[ty + i*8][tx] = f2b(s[(size_t)(k0 + ty + i*8) * N + n0 + tx]);
    __syncthreads();
    #pragma unroll
    for (int i = 0; i < 4; i++)
        d[(size_t)(n0 + ty + i*8) * K + k0 + tx] = tile[tx][ty + i*8];
}

// ------------------------------------------------------- adjacency / CSR ---
__global__ void adj_build(const int* __restrict__ src, const int* __restrict__ dst,
                          unsigned* __restrict__ adjbits)
{
    int t = blockIdx.x * blockDim.x + threadIdx.x;
    if (t < NEDGE) {
        int s = src[t], d = dst[t];
        atomicOr(&adjbits[(size_t)s*64 + (d >> 5)], 1u << (d & 31));
        atomicOr(&adjbits[(size_t)d*64 + (s >> 5)], 1u << (s & 31));
    }
    if (t < NNODE)
        atomicOr(&adjbits[(size_t)t*64 + (t >> 5)], 1u << (t & 31));
}

__global__ void row_rank(const unsigned* __restrict__ adjbits,
                         unsigned* __restrict__ rowcum, int* __restrict__ deg)
{
    int i = blockIdx.x * blockDim.x + threadIdx.x;
    if (i >= NNODE) return;
    unsigned c = 0;
    for (int w = 0; w < 64; w++) {
        rowcum[i*64 + w] = c;
        c += __popc(adjbits[i*64 + w]);
    }
    deg[i] = (int)c;
}

__global__ __launch_bounds__(256)
void scan_kernel(const int* __restrict__ deg, int* __restrict__ rowoff)
{
    __shared__ int part[256];
    int tid = threadIdx.x;
    int base = tid * 8;
    int local[8]; int s = 0;
    #pragma unroll
    for (int k = 0; k < 8; k++) { local[k] = s; s += deg[base + k]; }
    part[tid] = s;
    __syncthreads();
    for (int off = 1; off < 256; off <<= 1) {
        int v = (tid >= off) ? part[tid - off] : 0;
        __syncthreads();
        part[tid] += v;
        __syncthreads();
    }
    int pre = (tid == 0) ? 0 : part[tid - 1];
    #pragma unroll
    for (int k = 0; k < 8; k++) rowoff[base + k] = pre + local[k];
    if (tid == 255) rowoff[NNODE] = part[255];
}

// fill_cols (blocks 0..511) + edge_bias_scatter (blocks 512..8703), merged.
__global__ __launch_bounds__(256)
void csr_finish(const unsigned* __restrict__ adjbits, const int* __restrict__ rowoff,
                const unsigned* __restrict__ rowcum, int* __restrict__ cols,
                const float* __restrict__ ef, const float* __restrict__ Wcomb,
                const float* __restrict__ bcomb,
                const int* __restrict__ src, const int* __restrict__ dst,
                float* __restrict__ bias_csr)
{
    __shared__ float Wl[64*32];
    __shared__ float bl[32];
    int bid = blockIdx.x;
    if (bid < 512) {
        int t = bid * 256 + threadIdx.x;
        int i = t >> 6, w = t & 63;
        unsigned bits = adjbits[(size_t)i*64 + w];
        int base = rowoff[i] + (int)rowcum[(size_t)i*64 + w];
        while (bits) {
            int b = __ffs(bits) - 1;
            cols[base++] = w*32 + b;
            bits &= bits - 1;
        }
        return;
    }
    int tid = threadIdx.x;
    for (int k = tid; k < 64*32; k += 256) Wl[k] = Wcomb[k];
    if (tid < 32) bl[tid] = bcomb[tid];
    __syncthreads();
    int t = (bid - 512) * 256 + tid;
    int e = t >> 5, lh = t & 31;
    const float* f = ef + (size_t)e * 64;
    float acc = bl[lh];
    #pragma unroll
    for (int k = 0; k < 64; k++) acc += f[k] * Wl[k*32 + lh];
    int s = src[e], d = dst[e];
    unsigned wbits = adjbits[(size_t)s*64 + (d >> 5)];
    int rank = (int)rowcum[(size_t)s*64 + (d >> 5)] + __popc(wbits & ((1u << (d & 31)) - 1u));
    int slot = rowoff[s] + rank;
    atomicAdd(&bias_csr[(size_t)slot*32 + lh], acc);
}

// ------------------------------------------------------- sparse attention --
__global__ __launch_bounds__(256)
void attn_kernel(const unsigned short* __restrict__ QKVb, const int* __restrict__ rowoff,
                 const int* __restrict__ cols, const float* __restrict__ bias_csr,
                 unsigned short* __restrict__ ctxb, int layer)
{
    __shared__ float mS[4][8], lS[4][8];
    __shared__ __align__(16) float accS[4][256];
    int i = blockIdx.x;
    int tid = threadIdx.x;
    int w = tid >> 6, lane = tid & 63;
    int h = lane >> 3;
    int off = lane * 4;
    ushort4 qu = *(const ushort4*)(QKVb + (size_t)i*768 + off);
    float4 qf = { b2f(qu.x), b2f(qu.y), b2f(qu.z), b2f(qu.w) };
    int start = rowoff[i], end = rowoff[i+1];
    int lh0 = layer * 8 + h;
    float m = -INFINITY, l = 0.f;
    float4 acc = {0.f, 0.f, 0.f, 0.f};
    for (int c0 = start + w; c0 < end; c0 += 256) {
        int myslot = c0 + 4*lane;
        int mycol = (myslot < end) ? cols[myslot] : 0;
        int lim = min(end, c0 + 256);
        int it = 0;
        for (int slot = c0; slot < lim; slot += 4, ++it) {
            int j = __shfl(mycol, it);
            ushort4 ku = *(const ushort4*)(QKVb + (size_t)j*768 + 256 + off);
            float s = qf.x*b2f(ku.x) + qf.y*b2f(ku.y) + qf.z*b2f(ku.z) + qf.w*b2f(ku.w);
            s += __shfl_xor(s, 1);
            s += __shfl_xor(s, 2);
            s += __shfl_xor(s, 4);
            s = s * 0.17677669529663687f + bias_csr[(size_t)slot*32 + lh0];
            float mn = fmaxf(m, s);
            float sc = __expf(m - mn);
            float p  = __expf(s - mn);
            ushort4 vu = *(const ushort4*)(QKVb + (size_t)j*768 + 512 + off);
            acc.x = acc.x*sc + p*b2f(vu.x);
            acc.y = acc.y*sc + p*b2f(vu.y);
            acc.z = acc.z*sc + p*b2f(vu.z);
            acc.w = acc.w*sc + p*b2f(vu.w);
            l = l*sc + p;
            m = mn;
        }
    }
    if ((lane & 7) == 0) { mS[w][h] = m; lS[w][h] = l; }
    *(float4*)&accS[w][off] = acc;
    __syncthreads();
    if (w == 0) {
        float m0 = mS[0][h], m1 = mS[1][h], m2 = mS[2][h], m3 = mS[3][h];
        float mx = fmaxf(fmaxf(m0, m1), fmaxf(m2, m3));
        float e0 = (m0 == -INFINITY) ? 0.f : __expf(m0 - mx);
        float e1 = (m1 == -INFINITY) ? 0.f : __expf(m1 - mx);
        float e2 = (m2 == -INFINITY) ? 0.f : __expf(m2 - mx);
        float e3 = (m3 == -INFINITY) ? 0.f : __expf(m3 - mx);
        float ls = lS[0][h]*e0 + lS[1][h]*e1 + lS[2][h]*e2 + lS[3][h]*e3;
        float4 a0 = *(float4*)&accS[0][off];
        float4 a1 = *(float4*)&accS[1][off];
        float4 a2 = *(float4*)&accS[2][off];
        float4 a3 = *(float4*)&accS[3][off];
        float inv = 1.f / ls;
        ushort4 o;
        o.x = f2b((a0.x*e0 + a1.x*e1 + a2.x*e2 + a3.x*e3) * inv);
        o.y = f2b((a0.y*e0 + a1.y*e1 + a2.y*e2 + a3.y*e3) * inv);
        o.z = f2b((a0.z*e0 + a1.z*e1 + a2.z*e2 + a3.z*e3) * inv);
        o.w = f2b((a0.w*e0 + a1.w*e1 + a2.w*e2 + a3.w*e3) * inv);
        *(ushort4*)(ctxb + (size_t)i*HIDN + off) = o;
    }
}

// ------------------------------------------------------------ layernorm ----
template<bool RES>
__global__ __launch_bounds__(256)
void ln_kernel(float* __restrict__ x, const float* __restrict__ r,
               const float* __restrict__ g, const float* __restrict__ b,
               unsigned short* __restrict__ xb)
{
    __shared__ float lds[4];
    int row = blockIdx.x, c = threadIdx.x;
    float v = x[(size_t)row*HIDN + c];
    if (RES) v += r[(size_t)row*HIDN + c];
    float s = v;
    for (int mm = 1; mm < 64; mm <<= 1) s += __shfl_xor(s, mm);
    if ((c & 63) == 0) lds[c >> 6] = s;
    __syncthreads();
    float mean = (lds[0] + lds[1] + lds[2] + lds[3]) * (1.f / HIDN);
    __syncthreads();
    float dv = v - mean;
    float qq = dv * dv;
    for (int mm = 1; mm < 64; mm <<= 1) qq += __shfl_xor(qq, mm);
    if ((c & 63) == 0) lds[c >> 6] = qq;
    __syncthreads();
    float var = (lds[0] + lds[1] + lds[2] + lds[3]) * (1.f / HIDN);
    float rs = rsqrtf(var + 1e-5f);
    float o = dv * rs * g[c] + b[c];
    x[(size_t)row*HIDN + c] = o;
    xb[(size_t)row*HIDN + c] = f2b(o);
}

// ----------------------------------------- pooling: 16-block partials ------
__global__ __launch_bounds__(256)
void pool_part(const float* __restrict__ x, const float* __restrict__ sred,
               float* __restrict__ partial)
{
    __shared__ float red[4];
    __shared__ float aw[128];
    int b = blockIdx.x, tid = threadIdx.x;
    float mxs = -INFINITY;
    for (int r = tid; r < NNODE; r += 256) mxs = fmaxf(mxs, sred[r]);
    for (int mm = 1; mm < 64; mm <<= 1) mxs = fmaxf(mxs, __shfl_xor(mxs, mm));
    if ((tid & 63) == 0) red[tid >> 6] = mxs;
    __syncthreads();
    mxs = fmaxf(fmaxf(red[0], red[1]), fmaxf(red[2], red[3]));
    __syncthreads();
    float ss = 0.f;
    for (int r = tid; r < NNODE; r += 256) ss += __expf(sred[r] - mxs);
    for (int mm = 1; mm < 64; mm <<= 1) ss += __shfl_xor(ss, mm);
    if ((tid & 63) == 0) red[tid >> 6] = ss;
    __syncthreads();
    ss = red[0] + red[1] + red[2] + red[3];
    float inv = 1.f / ss;
    int r0 = b * 128;
    if (tid < 128) aw[tid] = __expf(sred[r0 + tid] - mxs) * inv;
    __syncthreads();
    float sm = 0.f, mx = -INFINITY, ap = 0.f;
    for (int r = 0; r < 128; r++) {
        float v = x[(size_t)(r0 + r)*HIDN + tid];
        sm += v;
        mx = fmaxf(mx, v);
        ap += v * aw[r];
    }
    partial[(size_t)b*768 + tid]       = sm;
    partial[(size_t)b*768 + 256 + tid] = mx;
    partial[(size_t)b*768 + 512 + tid] = ap;
}

// --------------------------------------------------------------- head ------
// head1 absorbs pool_fin: each of 8 blocks folds the 16 partials -> g (LDS),
// then computes its 64 h1 outputs (4-wave split-K over 768).
__global__ __launch_bounds__(256)
void head1(const float* __restrict__ partial, const float* __restrict__ Wo1,
           const float* __restrict__ bo1, float* __restrict__ h1)
{
    __shared__ float gs[768];
    __shared__ float hp[4][64];
    int tid = threadIdx.x;
    {
        float sm = 0.f, mx = -INFINITY, ap = 0.f;
        #pragma unroll
        for (int b = 0; b < 16; b++) {
            sm += partial[(size_t)b*768 + tid];
            mx = fmaxf(mx, partial[(size_t)b*768 + 256 + tid]);
            ap += partial[(size_t)b*768 + 512 + tid];
        }
        gs[tid]       = sm * (1.f / NNODE);
        gs[256 + tid] = mx;
        gs[512 + tid] = ap;
    }
    __syncthreads();
    int w = tid >> 6, lane = tid & 63;
    int j = blockIdx.x * 64 + lane;
    float acc = 0.f;
    int k0 = w * 192;
    for (int k = k0; k < k0 + 192; k++)
        acc += gs[k] * Wo1[(size_t)k*512 + j];
    hp[w][lane] = acc;
    __syncthreads();
    if (w == 0) {
        float s = hp[0][lane] + hp[1][lane] + hp[2][lane] + hp[3][lane] + bo1[j];
        h1[j] = fmaxf(s, 0.f);
    }
}

__global__ __launch_bounds__(256)
void head2(const float* __restrict__ h1, const float* __restrict__ Wo2,
           const float* __restrict__ bo2, float* __restrict__ out)
{
    __shared__ float hp[4][64];
    int tid = threadIdx.x;
    int w = tid >> 6, lane = tid & 63;
    int j = blockIdx.x * 64 + lane;
    float acc = 0.f;
    int k0 = w * 128;
    for (int k = k0; k < k0 + 128; k++)
        acc += h1[k] * Wo2[(size_t)k*OUTD + j];
    hp[w][lane] = acc;
    __syncthreads();
    if (w == 0)
        out[j] = hp[0][lane] + hp[1][lane] + hp[2][lane] + hp[3][lane] + bo2[j];
}

// ------------------------------------------------------------- launch ------
extern "C" void kernel_launch(void* const* d_in, const int* in_sizes, int n_in,
                              void* d_out, int out_size, void* d_ws, size_t ws_size,
                              hipStream_t stream)
{
    const float* node_features = (const float*)d_in[0];
    const float* edge_features = (const float*)d_in[1];
    const int*   edge_index    = (const int*)d_in[2];
    const float* W_node = (const float*)d_in[3];
    const float* b_node = (const float*)d_in[4];
    const float* W_edge = (const float*)d_in[5];
    const float* b_edge = (const float*)d_in[6];
    const float* pos_emb = (const float*)d_in[7];
    const float* Wq = (const float*)d_in[8];
    const float* bq = (const float*)d_in[9];
    const float* Wk = (const float*)d_in[10];
    const float* bk = (const float*)d_in[11];
    const float* Wv = (const float*)d_in[12];
    const float* bv = (const float*)d_in[13];
    const float* Wo = (const float*)d_in[14];
    const float* bo = (const float*)d_in[15];
    const float* Wep = (const float*)d_in[16];
    const float* bep = (const float*)d_in[17];
    const float* Wf1 = (const float*)d_in[18];
    const float* bf1 = (const float*)d_in[19];
    const float* Wf2 = (const float*)d_in[20];
    const float* bf2 = (const float*)d_in[21];
    const float* g1  = (const float*)d_in[22];
    const float* be1 = (const float*)d_in[23];
    const float* g2  = (const float*)d_in[24];
    const float* be2 = (const float*)d_in[25];
    const float* g_ln = (const float*)d_in[26];
    const float* b_ln = (const float*)d_in[27];
    const float* Wp1 = (const float*)d_in[28];
    const float* bp1 = (const float*)d_in[29];
    const float* Wp2 = (const float*)d_in[30];
    const float* bp2 = (const float*)d_in[31];
    const float* Wo1 = (const float*)d_in[32];
    const float* bo1 = (const float*)d_in[33];
    const float* Wo2 = (const float*)d_in[34];
    const float* bo2 = (const float*)d_in[35];
    (void)bp2;
    const int* src = edge_index;
    const int* dst = edge_index + NEDGE;

    char* w = (char*)d_ws;
    auto carve = [&](size_t nbytes) {
        void* p = (void*)w;
        w += (nbytes + 255) & ~(size_t)255;
        return p;
    };
    float* x        = (float*)carve((size_t)NNODE*HIDN*4);
    unsigned short* xb = (unsigned short*)carve((size_t)NNODE*HIDN*2);
    unsigned short* bufQKVb = (unsigned short*)carve((size_t)NNODE*768*2);
    float* bufO     = (float*)carve((size_t)NNODE*HIDN*4);
    unsigned short* bufAb = (unsigned short*)carve((size_t)NNODE*HIDN*2);
    unsigned short* bufFb = (unsigned short*)carve((size_t)NNODE*FFD*2);
    float* Wcomb    = (float*)carve(64*32*4);
    float* bcomb    = (float*)carve(32*4);
    // adjbits + bias_csr + sbuf contiguous -> single memset
    unsigned* adjbits = (unsigned*)carve((size_t)NNODE*64*4);
    float* bias_csr = (float*)carve((size_t)NNZ_MAX*32*4);
    float* sbuf  = (float*)carve(NNODE*4);
    unsigned* rowcum  = (unsigned*)carve((size_t)NNODE*64*4);
    int* deg    = (int*)carve(NNODE*4);
    int* rowoff = (int*)carve((NNODE+1)*4);
    int* colsb  = (int*)carve((size_t)NNZ_MAX*4);
    float* partial = (float*)carve(16*768*4);
    float* h1buf = (float*)carve(512*4);
    unsigned short* nf_b  = (unsigned short*)carve((size_t)NNODE*128*2);
    unsigned short* WnT   = (unsigned short*)carve((size_t)HIDN*128*2);
    unsigned short* WqkvT = (unsigned short*)carve((size_t)NLAYER*768*HIDN*2);
    float*          bqkv  = (float*)carve((size_t)NLAYER*768*4);
    unsigned short* WoT   = (unsigned short*)carve((size_t)NLAYER*HIDN*HIDN*2);
    unsigned short* Wf1T  = (unsigned short*)carve((size_t)NLAYER*FFD*HIDN*2);
    unsigned short* Wf2T  = (unsigned short*)carve((size_t)NLAYER*HIDN*FFD*2);
    unsigned short* Wp1T  = (unsigned short*)carve((size_t)HIDN*HIDN*2);

    // ---- zero adjbits + bias_csr + sbuf in one shot ----
    hipMemsetAsync(adjbits, 0,
                   (size_t)NNODE*64*4 + (size_t)NNZ_MAX*32*4 + (size_t)NNODE*4, stream);
    adj_build<<<(NEDGE+255)/256, 256, 0, stream>>>(src, dst, adjbits);
    row_rank<<<NNODE/256, 256, 0, stream>>>(adjbits, rowcum, deg);
    scan_kernel<<<1, 256, 0, stream>>>(deg, rowoff);

    // ---- weight prep (transposes + nf + biases + Wcomb) ----
    transpose_all<<<4204 + 9, 256, 0, stream>>>(
        Wq, Wk, Wv, Wo, Wf1, Wf2, W_node, Wp1,
        WqkvT, WoT, Wf1T, Wf2T, WnT, Wp1T,
        node_features, nf_b, bq, bk, bv, bqkv,
        W_edge, b_edge, Wep, bep, Wcomb, bcomb);

    // ---- CSR cols + edge-bias scatter (merged) ----
    csr_finish<<<512 + (NEDGE*32)/256, 256, 0, stream>>>(
        adjbits, rowoff, rowcum, colsb,
        edge_features, Wcomb, bcomb, src, dst, bias_csr);

    // ---- node encoding: x = nf @ W_node + b_node + pos_emb ----
    mgemm<128,3,2><<<dim3(HIDN/64, NNODE/32), 256, 0, stream>>>(
        nf_b, WnT, b_node, pos_emb, x, xb, NNODE, HIDN, nullptr, nullptr);

    // ---- transformer layers (R9-proven) ----
    for (int l = 0; l < NLAYER; l++) {
        mgemm<256,0,1><<<dim3(768/64, NNODE/32), 256, 0, stream>>>(
            xb, WqkvT + (size_t)l*768*HIDN, bqkv + l*768, nullptr, nullptr, bufQKVb, NNODE, 768, nullptr, nullptr);
        attn_kernel<<<NNODE, 256, 0, stream>>>(bufQKVb, rowoff, colsb, bias_csr, bufAb, l);
        mgemm<256,0,0><<<dim3(HIDN/64, NNODE/32), 256, 0, stream>>>(
            bufAb, WoT + (size_t)l*HIDN*HIDN, bo + l*HIDN, nullptr, bufO, nullptr, NNODE, HIDN, nullptr, nullptr);
        ln_kernel<true><<<NNODE, 256, 0, stream>>>(x, bufO, g1 + l*HIDN, be1 + l*HIDN, xb);
        mgemm<256,1,1><<<dim3(FFD/64, NNODE/32), 256, 0, stream>>>(
            xb, Wf1T + (size_t)l*FFD*HIDN, bf1 + l*FFD, nullptr, nullptr, bufFb, NNODE, FFD, nullptr, nullptr);
        mgemm<1024,0,0><<<dim3(HIDN/64, NNODE/32), 256, 0, stream>>>(
            bufFb, Wf2T + (size_t)l*HIDN*FFD, bf2 + l*HIDN, nullptr, bufO, nullptr, NNODE, HIDN, nullptr, nullptr);
        ln_kernel<true><<<NNODE, 256, 0, stream>>>(x, bufO, g2 + l*HIDN, be2 + l*HIDN, xb);
    }

    // ---- final LN + pooling (Wp1 GEMM fused with score reduce) + head ----
    ln_kernel<false><<<NNODE, 256, 0, stream>>>(x, nullptr, g_ln, b_ln, xb);
    mgemm<256,4,0><<<dim3(HIDN/64, NNODE/32), 256, 0, stream>>>(
        xb, Wp1T, bp1, nullptr, nullptr, nullptr, NNODE, HIDN, Wp2, sbuf);
    pool_part<<<16, 256, 0, stream>>>(x, sbuf, partial);
    head1<<<8, 256, 0, stream>>>(partial, Wo1, bo1, h1buf);
    head2<<<OUTD/64, 256, 0, stream>>>(h1buf, Wo2, bo2, (float*)d_out);
}